// Round 1
// baseline (1022.910 us; speedup 1.0000x reference)
//
#include <hip/hip_runtime.h>
#include <cstdint>

#define BB 2048
#define NN 128
#define DD 128
#define CHUNK 512

// ---------------- threefry2x32 (JAX-exact) ----------------
__device__ __forceinline__ void tf_round(uint32_t& x0, uint32_t& x1, int r) {
  x0 += x1; x1 = (x1 << r) | (x1 >> (32 - r)); x1 ^= x0;
}

__device__ __forceinline__ uint2 threefry(uint32_t k0, uint32_t k1, uint32_t x0, uint32_t x1) {
  uint32_t k2 = k0 ^ k1 ^ 0x1BD11BDAu;
  x0 += k0; x1 += k1;
  tf_round(x0,x1,13); tf_round(x0,x1,15); tf_round(x0,x1,26); tf_round(x0,x1,6);
  x0 += k1; x1 += k2 + 1u;
  tf_round(x0,x1,17); tf_round(x0,x1,29); tf_round(x0,x1,16); tf_round(x0,x1,24);
  x0 += k2; x1 += k0 + 2u;
  tf_round(x0,x1,13); tf_round(x0,x1,15); tf_round(x0,x1,26); tf_round(x0,x1,6);
  x0 += k0; x1 += k1 + 3u;
  tf_round(x0,x1,17); tf_round(x0,x1,29); tf_round(x0,x1,16); tf_round(x0,x1,24);
  x0 += k1; x1 += k2 + 4u;
  tf_round(x0,x1,13); tf_round(x0,x1,15); tf_round(x0,x1,26); tf_round(x0,x1,6);
  x0 += k2; x1 += k0 + 5u;
  uint2 r; r.x = x0; r.y = x1; return r;
}

__device__ __forceinline__ float gumbel_from_bits(uint32_t bits) {
  const float TINY = 1.17549435e-38f;
  float u = __uint_as_float(0x3F800000u | (bits >> 9)) - 1.0f;   // [0,1)
  u = u + TINY;                     // XLA: floats*(max-min)+min with (1-tiny)->1.0f
  u = fmaxf(TINY, u);
  return -logf(-logf(u));
}

// step keys: keys[i] = threefry((0,42),(0,i))  [partitionable split of key(42)]
__global__ void k_keys(uint2* __restrict__ keys) {
  int i = threadIdx.x;
  if (i < NN - 1) keys[i] = threefry(0u, 42u, 0u, (uint32_t)i);
}

// M = Wc2 @ Wq   (Wc rows 128..255 are the h_cur part)
__global__ void k_M(const float* __restrict__ Wc, const float* __restrict__ Wq,
                    float* __restrict__ M) {
  __shared__ __align__(16) float wrow[DD];
  int r = blockIdx.x, o = threadIdx.x;
  wrow[o] = Wc[(DD + r) * DD + o];
  __syncthreads();
  float acc = 0.f;
#pragma unroll 4
  for (int c = 0; c < DD; ++c) acc += wrow[c] * Wq[c * DD + o];
  M[r * DD + o] = acc;
}

// Qbase[b] = (graph[b]@Wc1 + bc) @ Wq + bq
__global__ void k_qbase(const float* __restrict__ graph, const float* __restrict__ Wc,
                        const float* __restrict__ bc, const float* __restrict__ Wq,
                        const float* __restrict__ bq, float* __restrict__ Qbase) {
  __shared__ __align__(16) float g[DD];
  __shared__ __align__(16) float c1[DD];
  int b = blockIdx.x, t = threadIdx.x;
  g[t] = graph[b * DD + t];
  __syncthreads();
  float acc = 0.f;
#pragma unroll 4
  for (int r = 0; r < DD; ++r) acc += g[r] * Wc[r * DD + t];
  c1[t] = acc + bc[t];
  __syncthreads();
  float acc2 = 0.f;
#pragma unroll 4
  for (int c = 0; c < DD; ++c) acc2 += c1[c] * Wq[c * DD + t];
  Qbase[b * DD + t] = acc2 + bq[t];
}

// K = h@Wk + bk ; QQ = h@M + Qbase[b]   (64 rows per block, chunk-local outputs)
__global__ __launch_bounds__(256) void k_kqq(
    const float* __restrict__ h, const float* __restrict__ Wk, const float* __restrict__ bk,
    const float* __restrict__ Mm, const float* __restrict__ Qbase,
    float* __restrict__ Kc, float* __restrict__ QQc, int b0) {
  __shared__ __align__(16) float As[64 * DD];
  int tid = threadIdx.x;
  int grow0 = b0 * NN + blockIdx.x * 64;  // global flat row (b*N+n)
  for (int t = tid * 4; t < 64 * DD; t += 1024) {
    int r = t >> 7, k = t & 127;
    *(float4*)&As[t] = *(const float4*)&h[(grow0 + r) * DD + k];
  }
  __syncthreads();
  int ty = tid >> 5, tx = tid & 31;
  float accK[8][4] = {{0}}, accQ[8][4] = {{0}};
  for (int k4 = 0; k4 < DD; k4 += 4) {
    float4 a4[8];
#pragma unroll
    for (int i = 0; i < 8; ++i) a4[i] = *(const float4*)&As[(ty * 8 + i) * DD + k4];
#pragma unroll
    for (int kk = 0; kk < 4; ++kk) {
      float4 w = *(const float4*)&Wk[(k4 + kk) * DD + tx * 4];
      float4 m = *(const float4*)&Mm[(k4 + kk) * DD + tx * 4];
#pragma unroll
      for (int i = 0; i < 8; ++i) {
        float a = ((const float*)&a4[i])[kk];
        accK[i][0] += a * w.x; accK[i][1] += a * w.y; accK[i][2] += a * w.z; accK[i][3] += a * w.w;
        accQ[i][0] += a * m.x; accQ[i][1] += a * m.y; accQ[i][2] += a * m.z; accQ[i][3] += a * m.w;
      }
    }
  }
  float4 bk4 = *(const float4*)&bk[tx * 4];
#pragma unroll
  for (int i = 0; i < 8; ++i) {
    int grow = grow0 + ty * 8 + i;
    int b = grow >> 7;                 // global batch
    int lrow = grow - b0 * NN;         // chunk-local row
    float4 qb = *(const float4*)&Qbase[b * DD + tx * 4];
    float4 ok, oq;
    ok.x = accK[i][0] + bk4.x; ok.y = accK[i][1] + bk4.y;
    ok.z = accK[i][2] + bk4.z; ok.w = accK[i][3] + bk4.w;
    oq.x = accQ[i][0] + qb.x;  oq.y = accQ[i][1] + qb.y;
    oq.z = accQ[i][2] + qb.z;  oq.w = accQ[i][3] + qb.w;
    *(float4*)&Kc[lrow * DD + tx * 4] = ok;
    *(float4*)&QQc[lrow * DD + tx * 4] = oq;
  }
}

// T[b,i,n] = 10*tanh( dot(QQ[b,i],K[b,n]) / 32 )   (block = one b, one 64-row i-tile)
__global__ __launch_bounds__(128) void k_score(
    const float* __restrict__ QQc, const float* __restrict__ Kc,
    float* __restrict__ T, int b0) {
  __shared__ __align__(16) float QQs[64 * 68];
  __shared__ __align__(16) float Ks[128 * 68];
  int bb = blockIdx.x >> 1;   // chunk-local b
  int it = blockIdx.x & 1;    // i-tile
  int tid = threadIdx.x;
  int ty = tid >> 4, tx = tid & 15;
  float acc[8][8] = {{0}};
  for (int kp = 0; kp < 2; ++kp) {
    for (int t = tid; t < 64 * 16; t += 128) {
      int r = t >> 4, kq = (t & 15) * 4;
      *(float4*)&QQs[r * 68 + kq] =
          *(const float4*)&QQc[(bb * NN + it * 64 + r) * DD + kp * 64 + kq];
    }
    for (int t = tid; t < 128 * 16; t += 128) {
      int n = t >> 4, kq = (t & 15) * 4;
      *(float4*)&Ks[n * 68 + kq] =
          *(const float4*)&Kc[(bb * NN + n) * DD + kp * 64 + kq];
    }
    __syncthreads();
    for (int k4 = 0; k4 < 64; k4 += 4) {
      float4 a[8], bv[8];
#pragma unroll
      for (int i = 0; i < 8; ++i) a[i] = *(const float4*)&QQs[(ty * 8 + i) * 68 + k4];
#pragma unroll
      for (int j = 0; j < 8; ++j) bv[j] = *(const float4*)&Ks[(j * 16 + tx) * 68 + k4];
#pragma unroll
      for (int i = 0; i < 8; ++i)
#pragma unroll
        for (int j = 0; j < 8; ++j)
          acc[i][j] += a[i].x * bv[j].x + a[i].y * bv[j].y +
                       a[i].z * bv[j].z + a[i].w * bv[j].w;
    }
    __syncthreads();
  }
  int b = b0 + bb;
#pragma unroll
  for (int i = 0; i < 8; ++i) {
    int row = it * 64 + ty * 8 + i;
#pragma unroll
    for (int j = 0; j < 8; ++j) {
      int n = j * 16 + tx;
      T[(b * NN + row) * NN + n] = 10.0f * tanhf(acc[i][j] * 0.03125f);
    }
  }
}

// sequential sampling: one wave per batch element; lane owns nodes (lane, lane+64)
__global__ __launch_bounds__(64) void k_decode(
    const float* __restrict__ T, const uint2* __restrict__ keys, float* __restrict__ out) {
  int b = blockIdx.x;
  int lane = threadIdx.x;
  __shared__ uint2 klds[NN - 1];
  for (int i = lane; i < NN - 1; i += 64) klds[i] = keys[i];
  __syncthreads();
  const int n0 = lane, n1 = lane + 64;
  bool vis0 = (n0 == 0), vis1 = false;
  float logp = 0.f;
  int cur = 0;
  if (lane == 0) out[b * NN] = 0.0f;
  for (int s = 0; s < NN - 1; ++s) {
    const float* row = T + (b * NN + cur) * NN;
    float sc0 = row[n0], sc1 = row[n1];
    uint2 k = klds[s];
    uint2 r0 = threefry(k.x, k.y, 0u, (uint32_t)(b * NN + n0));
    uint2 r1 = threefry(k.x, k.y, 0u, (uint32_t)(b * NN + n1));
    float g0 = gumbel_from_bits(r0.x ^ r0.y);
    float g1 = gumbel_from_bits(r1.x ^ r1.y);
    float v0 = vis0 ? -INFINITY : sc0 + g0;
    float v1 = vis1 ? -INFINITY : sc1 + g1;
    float bvv; int bi;
    if (v1 > v0) { bvv = v1; bi = n1; } else { bvv = v0; bi = n0; }
#pragma unroll
    for (int off = 32; off > 0; off >>= 1) {
      float ov = __shfl_xor(bvv, off);
      int oi = __shfl_xor(bi, off);
      if (ov > bvv || (ov == bvv && oi < bi)) { bvv = ov; bi = oi; }
    }
    int nxt = bi;  // uniform: global argmax, first-index tie-break
    float m = fmaxf(vis0 ? -INFINITY : sc0, vis1 ? -INFINITY : sc1);
#pragma unroll
    for (int off = 32; off > 0; off >>= 1) m = fmaxf(m, __shfl_xor(m, off));
    float e = (vis0 ? 0.f : expf(sc0 - m)) + (vis1 ? 0.f : expf(sc1 - m));
#pragma unroll
    for (int off = 32; off > 0; off >>= 1) e += __shfl_xor(e, off);
    float scn = (nxt < 64) ? __shfl(sc0, nxt) : __shfl(sc1, nxt - 64);
    logp += scn - m - logf(e);
    vis0 = vis0 || (n0 == nxt);
    vis1 = vis1 || (n1 == nxt);
    cur = nxt;
    if (lane == 0) out[b * NN + s + 1] = (float)nxt;
  }
  if (lane == 0) out[BB * NN + b] = logp;
}

extern "C" void kernel_launch(void* const* d_in, const int* in_sizes, int n_in,
                              void* d_out, int out_size, void* d_ws, size_t ws_size,
                              hipStream_t stream) {
  const float* h     = (const float*)d_in[0];
  const float* graph = (const float*)d_in[1];
  const float* Wq    = (const float*)d_in[2];
  const float* bq    = (const float*)d_in[3];
  const float* Wk    = (const float*)d_in[4];
  const float* bk    = (const float*)d_in[5];
  // d_in[6], d_in[7] = Wv, bv : computed-but-unused in reference
  const float* Wc    = (const float*)d_in[8];
  const float* bc    = (const float*)d_in[9];
  float* out = (float*)d_out;

  char* ws = (char*)d_ws;
  uint2* keys  = (uint2*)ws;                                   // 1 KB
  float* Mm    = (float*)(ws + 1024);                          // 64 KB
  float* Qbase = (float*)(ws + 1024 + 65536);                  // 1 MB
  size_t toff  = 1024 + 65536 + 1048576;
  float* T     = (float*)(ws + toff);                          // 134 MB
  size_t koff  = toff + (size_t)BB * NN * NN * 4;
  float* Kc    = (float*)(ws + koff);                          // 33.5 MB
  float* QQc   = (float*)(ws + koff + (size_t)CHUNK * NN * DD * 4); // 33.5 MB

  k_keys<<<1, 128, 0, stream>>>(keys);
  k_M<<<128, 128, 0, stream>>>(Wc, Wq, Mm);
  k_qbase<<<BB, 128, 0, stream>>>(graph, Wc, bc, Wq, bq, Qbase);
  for (int b0 = 0; b0 < BB; b0 += CHUNK) {
    k_kqq<<<CHUNK * NN / 64, 256, 0, stream>>>(h, Wk, bk, Mm, Qbase, Kc, QQc, b0);
    k_score<<<CHUNK * 2, 128, 0, stream>>>(QQc, Kc, T, b0);
  }
  k_decode<<<BB, 64, 0, stream>>>(T, keys, out);
}